// Round 1
// baseline (99.826 us; speedup 1.0000x reference)
//
#include <hip/hip_runtime.h>
#include <math.h>

#define S_LEN  2048
#define D_HEAD 128
#define QBLK   64
#define KVBLK  32
#define NWAVES 4

typedef __attribute__((ext_vector_type(4))) float f32x4;
typedef __attribute__((ext_vector_type(8))) short short8;

// RNE float -> bf16 (bits)
__device__ __forceinline__ unsigned short f2bf(float x) {
    union { float f; unsigned u; } v; v.f = x;
    unsigned r = v.u + 0x7fffu + ((v.u >> 16) & 1u);
    return (unsigned short)(r >> 16);
}
__device__ __forceinline__ unsigned pack2(unsigned short a, unsigned short b) {
    return (unsigned)a | ((unsigned)b << 16);
}

// Causal attention fwd: scores = QK^T, mask upper-tri with -INF, softmax(S/sqrt(D)), @V.
// bf16 MFMA internally, fp32 accumulate/softmax. One block = 64 Q rows of one batch.
__global__ __launch_bounds__(256, 2)
void attn_fwd(const float* __restrict__ Qg, const float* __restrict__ Kg,
              const float* __restrict__ Vg, float* __restrict__ Og)
{
    constexpr float CSC = 0.12751744f;   // log2(e)/sqrt(128): fold scale+base-2 into Q
    const int tid  = threadIdx.x;
    const int lane = tid & 63;
    const int w    = tid >> 6;
    const int bid  = blockIdx.x;
    const int b    = bid & 15;            // batch
    const int qb   = 31 - (bid >> 4);     // heavy (large q0) blocks first
    const int q0   = qb * QBLK;
    const int q0w  = q0 + w * 16;         // this wave's 16 Q rows

    const int qc = lane & 15;             // S-layout: q within 16
    const int g  = lane >> 4;             // lane group 0..3

    __shared__ __align__(16) unsigned short Klds[2][KVBLK * D_HEAD]; // [k][d], swizzled
    __shared__ __align__(16) unsigned short Vlds[2][D_HEAD * KVBLK]; // V^T [d][k], swizzled
    __shared__ __align__(16) unsigned short Plds[NWAVES][16 * KVBLK];// per-wave P, swizzled

    const size_t base = (size_t)b * S_LEN * D_HEAD;

    // ---- Q fragments (MFMA B operand), pre-scaled by CSC ----
    // B-frag: lane holds B[d = 8*g + j][col q = lane%16]  -> Q[q0w+qc][db*32 + 8g + j]
    short8 qf[4];
    {
        const float* qp = Qg + base + (size_t)(q0w + qc) * D_HEAD + g * 8;
        #pragma unroll
        for (int db = 0; db < 4; ++db) {
            float4 x0 = *(const float4*)(qp + db * 32);
            float4 x1 = *(const float4*)(qp + db * 32 + 4);
            float t[8] = {x0.x, x0.y, x0.z, x0.w, x1.x, x1.y, x1.z, x1.w};
            short8 f;
            #pragma unroll
            for (int j = 0; j < 8; ++j) f[j] = (short)f2bf(t[j] * CSC);
            qf[db] = f;
        }
    }

    // ---- staging thread->element maps ----
    const int kr  = tid >> 3;          // K: row 0..31
    const int kc0 = (tid & 7) * 16;    // K: 16 cols
    const int vc  = tid & 127;         // V: d column
    const int vr0 = (tid >> 7) * 16;   // V: 16 k rows

    float kreg[16];
    float vreg[16];

    auto load_tile = [&](int kv0) {    // global -> regs (coalesced)
        const float* kp = Kg + base + (size_t)(kv0 + kr) * D_HEAD + kc0;
        #pragma unroll
        for (int i = 0; i < 4; ++i) {
            float4 t = *(const float4*)(kp + i * 4);
            kreg[4*i+0] = t.x; kreg[4*i+1] = t.y; kreg[4*i+2] = t.z; kreg[4*i+3] = t.w;
        }
        const float* vp = Vg + base + (size_t)(kv0 + vr0) * D_HEAD + vc;
        #pragma unroll
        for (int j = 0; j < 16; ++j) vreg[j] = vp[(size_t)j * D_HEAD];
    };

    auto store_tile = [&](int buf) {   // regs -> LDS (bf16, XOR-swizzled rows)
        unsigned short hk[16];
        #pragma unroll
        for (int i = 0; i < 16; ++i) hk[i] = f2bf(kreg[i]);
        {
            int i0 = (kr * 128 + kc0)     ^ ((kr & 7) << 3);
            int i1 = (kr * 128 + kc0 + 8) ^ ((kr & 7) << 3);
            uint4 u0 = { pack2(hk[0],hk[1]),  pack2(hk[2],hk[3]),  pack2(hk[4],hk[5]),  pack2(hk[6],hk[7]) };
            uint4 u1 = { pack2(hk[8],hk[9]),  pack2(hk[10],hk[11]),pack2(hk[12],hk[13]),pack2(hk[14],hk[15]) };
            *(uint4*)&Klds[buf][i0] = u0;
            *(uint4*)&Klds[buf][i1] = u1;
        }
        unsigned short hv[16];
        #pragma unroll
        for (int j = 0; j < 16; ++j) hv[j] = f2bf(vreg[j]);
        {
            int j0 = (vc * 32 + vr0)     ^ ((vc & 7) << 3);
            int j1 = (vc * 32 + vr0 + 8) ^ ((vc & 7) << 3);
            uint4 u0 = { pack2(hv[0],hv[1]),  pack2(hv[2],hv[3]),  pack2(hv[4],hv[5]),  pack2(hv[6],hv[7]) };
            uint4 u1 = { pack2(hv[8],hv[9]),  pack2(hv[10],hv[11]),pack2(hv[12],hv[13]),pack2(hv[14],hv[15]) };
            *(uint4*)&Vlds[buf][j0] = u0;
            *(uint4*)&Vlds[buf][j1] = u1;
        }
    };

    // ---- online softmax state (S-layout: this lane's row is q = q0w+qc) ----
    f32x4 o[8] = {};                  // O C/D layout: o[db][r] = O[4g+r][db*16+qc]
    float m = -1e30f, lsum = 0.f;
    const int qidx = q0w + qc;

    const int n_tiles = q0 / KVBLK + 2;
    load_tile(0);
    store_tile(0);
    __syncthreads();

    for (int t = 0; t < n_tiles; ++t) {
        const int buf = t & 1;
        const int kv0 = t * KVBLK;
        if (t + 1 < n_tiles) load_tile((t + 1) * KVBLK);

        const bool active = kv0 <= q0w + 15;   // wave-uniform
        if (active) {
            // ---- swapped QK^T: st[t16] = K_tile16 . Q^T  (rows=k, cols=q) ----
            f32x4 st[2] = {{0.f,0.f,0.f,0.f},{0.f,0.f,0.f,0.f}};
            #pragma unroll
            for (int t16 = 0; t16 < 2; ++t16) {
                const int krow = t16 * 16 + qc;       // A-frag row = lane%16
                #pragma unroll
                for (int db = 0; db < 4; ++db) {
                    int idx = (krow * 128 + db * 32 + g * 8) ^ ((krow & 7) << 3);
                    short8 kf = *(const short8*)&Klds[buf][idx];
                    st[t16] = __builtin_amdgcn_mfma_f32_16x16x32_bf16(kf, qf[db], st[t16], 0, 0, 0);
                }
            }
            float s[8];
            #pragma unroll
            for (int t16 = 0; t16 < 2; ++t16)
                #pragma unroll
                for (int r = 0; r < 4; ++r) s[t16*4+r] = st[t16][r];

            // causal mask (only on diagonal-straddling tiles)
            const bool full = (kv0 + KVBLK - 1) <= q0w;
            if (!full) {
                #pragma unroll
                for (int t16 = 0; t16 < 2; ++t16)
                    #pragma unroll
                    for (int r = 0; r < 4; ++r) {
                        int kidx = kv0 + t16 * 16 + g * 4 + r;
                        if (kidx > qidx) s[t16*4+r] = -1e30f;
                    }
            }

            // row max over 8 regs + lane-groups {l, l^16, l^32, l^48}
            float mx = s[0];
            #pragma unroll
            for (int i = 1; i < 8; ++i) mx = fmaxf(mx, s[i]);
            mx = fmaxf(mx, __shfl_xor(mx, 16));
            mx = fmaxf(mx, __shfl_xor(mx, 32));
            float mnew = fmaxf(m, mx);
            float alpha = exp2f(m - mnew);
            m = mnew;

            float p[8], rs = 0.f;
            #pragma unroll
            for (int i = 0; i < 8; ++i) { p[i] = exp2f(s[i] - mnew); rs += p[i]; }
            rs += __shfl_xor(rs, 16);
            rs += __shfl_xor(rs, 32);
            lsum = lsum * alpha + rs;

            // rescale O (needs alpha in O-layout rows 4g+r; source lanes 0..15 hold q=lane)
            float a_o[4];
            #pragma unroll
            for (int r = 0; r < 4; ++r) a_o[r] = __shfl(alpha, g * 4 + r);
            #pragma unroll
            for (int db = 0; db < 8; ++db)
                #pragma unroll
                for (int r = 0; r < 4; ++r) o[db][r] *= a_o[r];

            // write P (bf16) to wave-private LDS:  P[q=qc][k = 16*t16 + 4g + r]
            uint2 w0, w1;
            w0.x = pack2(f2bf(p[0]), f2bf(p[1])); w0.y = pack2(f2bf(p[2]), f2bf(p[3]));
            w1.x = pack2(f2bf(p[4]), f2bf(p[5])); w1.y = pack2(f2bf(p[6]), f2bf(p[7]));
            int pi0 = (qc * 32 + g * 4)      ^ ((qc & 7) << 3);
            int pi1 = (qc * 32 + 16 + g * 4) ^ ((qc & 7) << 3);
            *(uint2*)&Plds[w][pi0] = w0;
            *(uint2*)&Plds[w][pi1] = w1;
        }
        __syncthreads();   // P visibility (cross-lane, same wave) + keeps waves in cadence
        if (active) {
            // ---- PV: A = P (row q=lane%16, k=8g+j), B = V^T read per d-block ----
            int pai = (qc * 32 + g * 8) ^ ((qc & 7) << 3);
            short8 pa = *(const short8*)&Plds[w][pai];
            #pragma unroll
            for (int db = 0; db < 8; ++db) {
                int d = db * 16 + qc;
                int vi = (d * 32 + g * 8) ^ ((d & 7) << 3);
                short8 vf = *(const short8*)&Vlds[buf][vi];
                o[db] = __builtin_amdgcn_mfma_f32_16x16x32_bf16(pa, vf, o[db], 0, 0, 0);
            }
        }
        if (t + 1 < n_tiles) store_tile(buf ^ 1);  // buf^1 free since last iter's barrier
        __syncthreads();
    }

    // ---- epilogue: 1/l in O-layout, store ----
    float linv = 1.0f / lsum;
    float li[4];
    #pragma unroll
    for (int r = 0; r < 4; ++r) li[r] = __shfl(linv, g * 4 + r);
    #pragma unroll
    for (int db = 0; db < 8; ++db)
        #pragma unroll
        for (int r = 0; r < 4; ++r) {
            int row = q0w + g * 4 + r;
            Og[base + (size_t)row * D_HEAD + db * 16 + qc] = o[db][r] * li[r];
        }
}

extern "C" void kernel_launch(void* const* d_in, const int* in_sizes, int n_in,
                              void* d_out, int out_size, void* d_ws, size_t ws_size,
                              hipStream_t stream) {
    const float* Q = (const float*)d_in[0];
    const float* K = (const float*)d_in[1];
    const float* V = (const float*)d_in[2];
    float* O = (float*)d_out;
    dim3 grid(16 * (S_LEN / QBLK));   // 512: batch-major within a q-block rank
    dim3 block(256);
    attn_fwd<<<grid, block, 0, stream>>>(Q, K, V, O);
}